// Round 1
// baseline (41.899 us; speedup 1.0000x reference)
//
#include <hip/hip_runtime.h>
#include <math.h>

#define NQ 12
#define NN 4096   // 2^12

__device__ __forceinline__ float2 cmul(float2 a, float2 b) {
    return make_float2(a.x * b.x - a.y * b.y, a.x * b.y + a.y * b.x);
}
__device__ __forceinline__ float2 cmadd(float2 a, float2 b, float2 acc) {
    acc.x = fmaf(a.x, b.x, fmaf(-a.y, b.y, acc.x));
    acc.y = fmaf(a.x, b.y, fmaf(a.y, b.x, acc.y));
    return acc;
}

// d_ws layout (float2): [p*4 + {m00,m01,m10,m11}] for p=0..11, then [48..63] = T[w*4+w']
// where T = M9 (x) M8 acting on the wave-index pair of bits (8,9), w = (b9<<1)|b8.
__global__ void setup_mats(const float* __restrict__ alphas,
                           const float* __restrict__ betas,
                           const float* __restrict__ thetas,
                           const float* __restrict__ phis,
                           float2* __restrict__ Mg) {
    __shared__ float2 Ms[48];
    int t = threadIdx.x;
    if (t < NQ) {
        int p = t;            // bit position of index i
        int q = NQ - 1 - p;   // parameter index (phase_shifts uses bit_{n-1-q})
        float sa, ca, sb, cb, st, ct, sf, cf;
        sincosf(alphas[q], &sa, &ca);
        sincosf(betas[q],  &sb, &cb);
        sincosf(thetas[q], &st, &ct);
        sincosf(phis[q],   &sf, &cf);
        float2 A  = make_float2(ca, sa);     // e^{i alpha}
        float2 Bb = make_float2(cb, sb);     // e^{i beta}
        float2 F  = make_float2(cf, sf);     // e^{i phi}
        // (T-1)/2 and (T+1)/2, T = e^{i theta}
        float2 Tm  = make_float2(0.5f * (ct - 1.0f), 0.5f * st);
        float2 Tp  = make_float2(0.5f * (ct + 1.0f), 0.5f * st);
        float2 iTp = make_float2(-Tp.y, Tp.x);  // i*(T+1)/2
        // M = diag(F,1) * [[Tm, iTp],[iTp, -Tm]] * diag(A, Bb)
        float2 m00 = cmul(cmul(F, Tm), A);
        float2 m01 = cmul(cmul(F, iTp), Bb);
        float2 m10 = cmul(iTp, A);
        float2 m11 = cmul(make_float2(-Tm.x, -Tm.y), Bb);
        Ms[p * 4 + 0] = m00; Ms[p * 4 + 1] = m01;
        Ms[p * 4 + 2] = m10; Ms[p * 4 + 3] = m11;
        Mg[p * 4 + 0] = m00; Mg[p * 4 + 1] = m01;
        Mg[p * 4 + 2] = m10; Mg[p * 4 + 3] = m11;
    }
    __syncthreads();
    if (t < 16) {
        int w = t >> 2, wp = t & 3;
        int b9 = w >> 1, b8 = w & 1, b9p = wp >> 1, b8p = wp & 1;
        Mg[48 + t] = cmul(Ms[9 * 4 + b9 * 2 + b9p], Ms[8 * 4 + b8 * 2 + b8p]);
    }
}

// One block per batch row. Thread t holds 16 complex elements:
//   i = (rhi<<10) | (t<<2) | c,  slot s = rhi*4 + c.
// Stages (all commute; each is a generic 2x2 complex butterfly on one bit):
//   bits 0,1   -> in-register (c)
//   bits 2..7  -> __shfl_xor (lane bits)
//   bits 10,11 -> in-register (rhi)
//   bits 8,9   -> one LDS gather across the 4 waves with T = M9 (x) M8
__global__ __launch_bounds__(256) void sq_layer(const float* __restrict__ x,
                                                const float2* __restrict__ Mg,
                                                float* __restrict__ out) {
    __shared__ float2 lds[16][256];  // 32 KB
    const int t = threadIdx.x;
    const int lane = t & 63;
    const size_t rowoff = (size_t)blockIdx.x * (2 * NN);

    float2 v[16];
    #pragma unroll
    for (int rhi = 0; rhi < 4; ++rhi) {
        int base = (rhi << 10) + (t << 2);
        float4 re4 = *reinterpret_cast<const float4*>(x + rowoff + base);
        float4 im4 = *reinterpret_cast<const float4*>(x + rowoff + NN + base);
        v[rhi * 4 + 0] = make_float2(re4.x, im4.x);
        v[rhi * 4 + 1] = make_float2(re4.y, im4.y);
        v[rhi * 4 + 2] = make_float2(re4.z, im4.z);
        v[rhi * 4 + 3] = make_float2(re4.w, im4.w);
    }

    // ---- bit 0 (c bit 0): pairs (s, s+1), s even ----
    {
        float2 m00 = Mg[0], m01 = Mg[1], m10 = Mg[2], m11 = Mg[3];
        #pragma unroll
        for (int s = 0; s < 16; s += 2) {
            float2 va = v[s], vb = v[s + 1];
            float2 r0 = cmul(m00, va); r0 = cmadd(m01, vb, r0);
            float2 r1 = cmul(m10, va); r1 = cmadd(m11, vb, r1);
            v[s] = r0; v[s + 1] = r1;
        }
    }
    // ---- bit 1 (c bit 1): pairs (s, s+2) within each rhi group ----
    {
        float2 m00 = Mg[4], m01 = Mg[5], m10 = Mg[6], m11 = Mg[7];
        #pragma unroll
        for (int g = 0; g < 4; ++g) {
            #pragma unroll
            for (int k = 0; k < 2; ++k) {
                int s = g * 4 + k;
                float2 va = v[s], vb = v[s + 2];
                float2 r0 = cmul(m00, va); r0 = cmadd(m01, vb, r0);
                float2 r1 = cmul(m10, va); r1 = cmadd(m11, vb, r1);
                v[s] = r0; v[s + 2] = r1;
            }
        }
    }
    // ---- bits 2..7: shuffle butterflies (lane bits 0..5) ----
    #pragma unroll
    for (int p = 2; p <= 7; ++p) {
        const int m = 1 << (p - 2);
        float2 m00 = Mg[p * 4 + 0], m01 = Mg[p * 4 + 1];
        float2 m10 = Mg[p * 4 + 2], m11 = Mg[p * 4 + 3];
        int bit = (lane >> (p - 2)) & 1;
        // bit==0: new = m00*my + m01*partner ; bit==1: new = m11*my + m10*partner
        float2 A  = bit ? m11 : m00;
        float2 Bc = bit ? m10 : m01;
        #pragma unroll
        for (int s = 0; s < 16; ++s) {
            float pr = __shfl_xor(v[s].x, m, 64);
            float pi = __shfl_xor(v[s].y, m, 64);
            float2 r = cmul(A, v[s]);
            r = cmadd(Bc, make_float2(pr, pi), r);
            v[s] = r;
        }
    }
    // ---- bit 10 (rhi bit 0): pairs (rhi 0,1) and (rhi 2,3) ----
    {
        float2 m00 = Mg[40], m01 = Mg[41], m10 = Mg[42], m11 = Mg[43];
        #pragma unroll
        for (int c = 0; c < 4; ++c) {
            {
                float2 va = v[c], vb = v[4 + c];
                float2 r0 = cmul(m00, va); r0 = cmadd(m01, vb, r0);
                float2 r1 = cmul(m10, va); r1 = cmadd(m11, vb, r1);
                v[c] = r0; v[4 + c] = r1;
            }
            {
                float2 va = v[8 + c], vb = v[12 + c];
                float2 r0 = cmul(m00, va); r0 = cmadd(m01, vb, r0);
                float2 r1 = cmul(m10, va); r1 = cmadd(m11, vb, r1);
                v[8 + c] = r0; v[12 + c] = r1;
            }
        }
    }
    // ---- bit 11 (rhi bit 1): pairs (rhi 0,2) and (rhi 1,3) ----
    {
        float2 m00 = Mg[44], m01 = Mg[45], m10 = Mg[46], m11 = Mg[47];
        #pragma unroll
        for (int c = 0; c < 4; ++c) {
            {
                float2 va = v[c], vb = v[8 + c];
                float2 r0 = cmul(m00, va); r0 = cmadd(m01, vb, r0);
                float2 r1 = cmul(m10, va); r1 = cmadd(m11, vb, r1);
                v[c] = r0; v[8 + c] = r1;
            }
            {
                float2 va = v[4 + c], vb = v[12 + c];
                float2 r0 = cmul(m00, va); r0 = cmadd(m01, vb, r0);
                float2 r1 = cmul(m10, va); r1 = cmadd(m11, vb, r1);
                v[4 + c] = r0; v[12 + c] = r1;
            }
        }
    }
    // ---- bits 8,9 (wave index bits): one LDS gather, apply T = M9 (x) M8 ----
    #pragma unroll
    for (int s = 0; s < 16; ++s) lds[s][t] = v[s];
    __syncthreads();
    {
        const int w = t >> 6;  // w = (bit9<<1)|bit8
        const float2* Tg = Mg + 48;
        float2 Tw0 = Tg[w * 4 + w];
        float2 Tw1 = Tg[w * 4 + (w ^ 1)];
        float2 Tw2 = Tg[w * 4 + (w ^ 2)];
        float2 Tw3 = Tg[w * 4 + (w ^ 3)];
        #pragma unroll
        for (int s = 0; s < 16; ++s) {
            float2 p1 = lds[s][t ^ 64];    // partner with bit8 flipped
            float2 p2 = lds[s][t ^ 128];   // bit9 flipped
            float2 p3 = lds[s][t ^ 192];   // both flipped
            float2 r = cmul(Tw0, v[s]);
            r = cmadd(Tw1, p1, r);
            r = cmadd(Tw2, p2, r);
            r = cmadd(Tw3, p3, r);
            v[s] = r;
        }
    }

    #pragma unroll
    for (int rhi = 0; rhi < 4; ++rhi) {
        int base = (rhi << 10) + (t << 2);
        float4 re4 = make_float4(v[rhi * 4 + 0].x, v[rhi * 4 + 1].x,
                                 v[rhi * 4 + 2].x, v[rhi * 4 + 3].x);
        float4 im4 = make_float4(v[rhi * 4 + 0].y, v[rhi * 4 + 1].y,
                                 v[rhi * 4 + 2].y, v[rhi * 4 + 3].y);
        *reinterpret_cast<float4*>(out + rowoff + base) = re4;
        *reinterpret_cast<float4*>(out + rowoff + NN + base) = im4;
    }
}

extern "C" void kernel_launch(void* const* d_in, const int* in_sizes, int n_in,
                              void* d_out, int out_size, void* d_ws, size_t ws_size,
                              hipStream_t stream) {
    const float* x      = (const float*)d_in[0];
    const float* alphas = (const float*)d_in[1];
    const float* betas  = (const float*)d_in[2];
    const float* thetas = (const float*)d_in[3];
    const float* phis   = (const float*)d_in[4];
    float* out = (float*)d_out;
    float2* Mg = (float2*)d_ws;   // 64 float2 = 512 B

    const int B = in_sizes[0] / (2 * NN);  // 2048

    hipLaunchKernelGGL(setup_mats, dim3(1), dim3(64), 0, stream,
                       alphas, betas, thetas, phis, Mg);
    hipLaunchKernelGGL(sq_layer, dim3(B), dim3(256), 0, stream, x, Mg, out);
}

// Round 2
// 39.120 us; speedup vs baseline: 1.0710x; 1.0710x over previous
//
#include <hip/hip_runtime.h>
#include <math.h>

#define NQ 12
#define NN 4096   // 2^12

__device__ __forceinline__ float2 cmul(float2 a, float2 b) {
    return make_float2(a.x * b.x - a.y * b.y, a.x * b.y + a.y * b.x);
}
__device__ __forceinline__ float2 cmadd(float2 a, float2 b, float2 acc) {
    acc.x = fmaf(a.x, b.x, fmaf(-a.y, b.y, acc.x));
    acc.y = fmaf(a.x, b.y, fmaf(a.y, b.x, acc.y));
    return acc;
}

// d_ws layout (float2): Mg[p*4 + {m00,m01,m10,m11}] for bit position p = 0..11.
// M_p = diag(e^{i phi},1) * u * diag(e^{i theta},1) * u * diag(e^{i alpha}, e^{i beta})
// with u = (1/sqrt2)[[1,i],[i,1]], parameters indexed q = 11-p.
__global__ void setup_mats(const float* __restrict__ alphas,
                           const float* __restrict__ betas,
                           const float* __restrict__ thetas,
                           const float* __restrict__ phis,
                           float2* __restrict__ Mg) {
    int t = threadIdx.x;
    if (t < NQ) {
        int p = t;            // bit position of index i
        int q = NQ - 1 - p;   // parameter index (phase_shifts uses bit_{n-1-q})
        float sa, ca, sb, cb, st, ct, sf, cf;
        sincosf(alphas[q], &sa, &ca);
        sincosf(betas[q],  &sb, &cb);
        sincosf(thetas[q], &st, &ct);
        sincosf(phis[q],   &sf, &cf);
        float2 A  = make_float2(ca, sa);     // e^{i alpha}
        float2 Bb = make_float2(cb, sb);     // e^{i beta}
        float2 F  = make_float2(cf, sf);     // e^{i phi}
        float2 Tm  = make_float2(0.5f * (ct - 1.0f), 0.5f * st);  // (T-1)/2
        float2 Tp  = make_float2(0.5f * (ct + 1.0f), 0.5f * st);  // (T+1)/2
        float2 iTp = make_float2(-Tp.y, Tp.x);                    // i*(T+1)/2
        Mg[p * 4 + 0] = cmul(cmul(F, Tm), A);
        Mg[p * 4 + 1] = cmul(cmul(F, iTp), Bb);
        Mg[p * 4 + 2] = cmul(iTp, A);
        Mg[p * 4 + 3] = cmul(make_float2(-Tm.x, -Tm.y), Bb);
    }
}

// LDS address swizzle: XOR low-4 element bits with bits [7:4].
// Puts every b64 transpose access pattern at the 4-access/bank floor.
__device__ __forceinline__ int swz(int i) { return i ^ ((i >> 4) & 0xF); }

// Generic radix-2 butterfly on slot bit log2(D) with 2x2 complex matrix m.
template<int D>
__device__ __forceinline__ void stage(float2 (&v)[16],
                                      float2 m00, float2 m01,
                                      float2 m10, float2 m11) {
    #pragma unroll
    for (int s = 0; s < 16; ++s) {
        if (s & D) continue;
        float2 va = v[s], vb = v[s | D];
        float2 r0 = cmul(m00, va); r0 = cmadd(m01, vb, r0);
        float2 r1 = cmul(m10, va); r1 = cmadd(m11, vb, r1);
        v[s] = r0; v[s | D] = r1;
    }
}

// One block per batch row; thread T holds 16 complex elements.
// Phase 1 (mapping A): i = rhi<<10 | T<<2 | c, slot = rhi*4+c -> bits {0,1,10,11}
// Phase 2 (mapping B): i = T[7:6]<<10 | T[5:2]<<6 | s<<2 | T[1:0] -> bits {2..5}
// Phase 3 (mapping C): i = T[7:6]<<10 | s<<6 | T[5:0] -> bits {6..9}
// Two LDS transposes between phases; all stages commute (distinct bits).
__global__ __launch_bounds__(256) void sq_layer(const float* __restrict__ x,
                                                const float2* __restrict__ Mg,
                                                float* __restrict__ out) {
    __shared__ float2 lds[NN];  // 32 KB
    const int T = threadIdx.x;
    const size_t rowoff = (size_t)blockIdx.x * (2 * NN);

    float2 v[16];
    // ---- load (mapping A), coalesced float4 ----
    #pragma unroll
    for (int rhi = 0; rhi < 4; ++rhi) {
        int base = (rhi << 10) + (T << 2);
        float4 re4 = *reinterpret_cast<const float4*>(x + rowoff + base);
        float4 im4 = *reinterpret_cast<const float4*>(x + rowoff + NN + base);
        v[rhi * 4 + 0] = make_float2(re4.x, im4.x);
        v[rhi * 4 + 1] = make_float2(re4.y, im4.y);
        v[rhi * 4 + 2] = make_float2(re4.z, im4.z);
        v[rhi * 4 + 3] = make_float2(re4.w, im4.w);
    }

    // ---- phase 1: bits 0 (d=1), 1 (d=2), 10 (d=4), 11 (d=8) ----
    stage<1>(v, Mg[0],  Mg[1],  Mg[2],  Mg[3]);    // bit 0
    stage<2>(v, Mg[4],  Mg[5],  Mg[6],  Mg[7]);    // bit 1
    stage<4>(v, Mg[40], Mg[41], Mg[42], Mg[43]);   // bit 10
    stage<8>(v, Mg[44], Mg[45], Mg[46], Mg[47]);   // bit 11

    // ---- transpose A -> B ----
    #pragma unroll
    for (int s = 0; s < 16; ++s) {
        int i = ((s >> 2) << 10) | (T << 2) | (s & 3);
        lds[swz(i)] = v[s];
    }
    __syncthreads();
    const int bB = ((T >> 6) << 10) | (((T >> 2) & 0xF) << 6) | (T & 3);
    #pragma unroll
    for (int s = 0; s < 16; ++s) v[s] = lds[swz(bB | (s << 2))];

    // ---- phase 2: bits 2,3,4,5 ----
    stage<1>(v, Mg[8],  Mg[9],  Mg[10], Mg[11]);   // bit 2
    stage<2>(v, Mg[12], Mg[13], Mg[14], Mg[15]);   // bit 3
    stage<4>(v, Mg[16], Mg[17], Mg[18], Mg[19]);   // bit 4
    stage<8>(v, Mg[20], Mg[21], Mg[22], Mg[23]);   // bit 5

    // ---- transpose B -> C (write-back hits only this thread's own
    //      read addresses, so no barrier needed before the writes) ----
    #pragma unroll
    for (int s = 0; s < 16; ++s) lds[swz(bB | (s << 2))] = v[s];
    __syncthreads();
    const int bC = ((T >> 6) << 10) | (T & 63);
    #pragma unroll
    for (int s = 0; s < 16; ++s) v[s] = lds[swz(bC | (s << 6))];

    // ---- phase 3: bits 6,7,8,9 ----
    stage<1>(v, Mg[24], Mg[25], Mg[26], Mg[27]);   // bit 6
    stage<2>(v, Mg[28], Mg[29], Mg[30], Mg[31]);   // bit 7
    stage<4>(v, Mg[32], Mg[33], Mg[34], Mg[35]);   // bit 8
    stage<8>(v, Mg[36], Mg[37], Mg[38], Mg[39]);   // bit 9

    // ---- store (mapping C): per slot, 64 consecutive dwords per wave ----
    #pragma unroll
    for (int s = 0; s < 16; ++s) {
        int i = bC | (s << 6);
        out[rowoff + i]      = v[s].x;
        out[rowoff + NN + i] = v[s].y;
    }
}

extern "C" void kernel_launch(void* const* d_in, const int* in_sizes, int n_in,
                              void* d_out, int out_size, void* d_ws, size_t ws_size,
                              hipStream_t stream) {
    const float* x      = (const float*)d_in[0];
    const float* alphas = (const float*)d_in[1];
    const float* betas  = (const float*)d_in[2];
    const float* thetas = (const float*)d_in[3];
    const float* phis   = (const float*)d_in[4];
    float* out = (float*)d_out;
    float2* Mg = (float2*)d_ws;   // 48 float2 = 384 B

    const int B = in_sizes[0] / (2 * NN);  // 2048

    hipLaunchKernelGGL(setup_mats, dim3(1), dim3(64), 0, stream,
                       alphas, betas, thetas, phis, Mg);
    hipLaunchKernelGGL(sq_layer, dim3(B), dim3(256), 0, stream, x, Mg, out);
}